// Round 9
// baseline (306.965 us; speedup 1.0000x reference)
//
#include <hip/hip_runtime.h>
#include <math.h>

// ---------------------------------------------------------------------------
// MLPAC_4_team fused v9: B=65536, P=3.
// v6 -> v9 (v7/v8's 512-thread detour reverted): 256-thread blocks, but LDS
// overlaid into one 36,864 B arena (enc-group buffer shrunk to 4 kt, obs+Hs
// overlap the h1/h2 region) -> 4 blocks/CU = 16 waves/CU (was 3 -> 12).
// Enc production: 5 groups (4,4,4,4,2 kts), 1 kt/wave. Fast exp-based tanh.
// prep_kernel unchanged from v6. ~80us of bench total is fixed harness cost.
// ---------------------------------------------------------------------------

#define NEG_SLOPE 0.01f

// ws offsets in ushort elements
#define OFF_B1A  0
#define OFF_ENCB 9216
#define OFF_PW1  175104
#define OFF_PW2  617472
#define OFF_PW3  814080
#define WS_TOTAL 826368

// tile (512-short) boundaries
#define TILE_ENCB 18
#define TILE_PW1  342
#define TILE_PW2  1206
#define TILE_PW3  1590

#define OBS_STRIDE 48     // shorts/row
#define HS_STRIDE  104    // shorts/row (96 used: ext0|ext1|opp)
#define ENC_STRIDE 136    // shorts/row (4*32 used + 8 pad)
#define H_STRIDE   264    // shorts/row (256 used)

// smem arena offsets (shorts): enc 64*136=8704 | obs 64*48=3072 | Hs 64*104=6656
#define SM_OBS 8704
#define SM_HS  11776
#define SM_TOT 18432      // 36864 B -> 4 blocks/CU

typedef short bf16x8 __attribute__((ext_vector_type(8)));
typedef float f32x4  __attribute__((ext_vector_type(4)));
typedef float f32x2  __attribute__((ext_vector_type(2)));

__device__ __forceinline__ float lrelu(float x) { return fmaxf(x, NEG_SLOPE * x); }

__device__ __forceinline__ f32x4 lrelu4(f32x4 x) {
  return __builtin_elementwise_max(x, x * NEG_SLOPE);
}
__device__ __forceinline__ f32x4 splat4(float b) { return (f32x4){b, b, b, b}; }

__device__ __forceinline__ float u2f(unsigned int u) {
  union { unsigned int u; float f; } c; c.u = u; return c.f;
}

__device__ __forceinline__ float fast_tanh(float x) {
  x = fminf(15.f, fmaxf(-15.f, x));
  float e = __expf(2.f * x);
  return (e - 1.f) / (e + 1.f);
}

// pack two f32 -> two bf16 (round-half-up) in one v_perm_b32
__device__ __forceinline__ unsigned int pk2bf(float a, float b) {
  union { float f; unsigned int u; } ca, cb; ca.f = a; cb.f = b;
  return __builtin_amdgcn_perm(cb.u + 0x8000u, ca.u + 0x8000u, 0x07060302u);
}

__device__ __forceinline__ unsigned short f2bf(float x) {  // RNE, prep only
  union { float f; unsigned int u; } c; c.f = x;
  unsigned int u = (c.u + 0x7fffu + ((c.u >> 16) & 1u)) >> 16;
  return (unsigned short)u;
}

// ---------------------------------------------------------------------------
// prep (v6): one thread = one frag row (lane) = 8 shorts = one uint4 store.
// B-frag layout: lane l holds B[k_pos=(l>>4)*8+j][n=l&15], j=0..7.
// kperm = (k_pos&1)*16 + (k_pos>>1) absorbs the pair-pack column permutation.
// ---------------------------------------------------------------------------
__global__ __launch_bounds__(256) void prep_kernel(
    const float* __restrict__ propW2, const float* __restrict__ extW1,
    const float* __restrict__ extW2,  const float* __restrict__ oppW1,
    const float* __restrict__ oppW2,  const float* __restrict__ piW1,
    const float* __restrict__ piW2,   const float* __restrict__ piW3,
    unsigned short* __restrict__ ws16)
{
  const int u = blockIdx.x * 256 + threadIdx.x;   // frag-row index
  if (u >= (WS_TOTAL >> 3)) return;
  const int lane = u & 63;
  const int t = u >> 6;                            // 512-short tile index
  const int lm = lane & 15;
  const int kbase = (lane >> 4) << 3;              // k_pos = kbase + j

  unsigned short o8[8];

  if (t < TILE_ENCB) {
    int s = t;
    const int nt2 = s & 1; s >>= 1;
    const int go = s % 3; const int p = s / 3;
    const int n = go * 32 + nt2 * 16 + lm;
    #pragma unroll
    for (int j = 0; j < 8; ++j) {
      const int d = 16 + kbase + j;
      float v;
      if (n < 64) {
        const int g = n >> 5, o = n & 31, i = d - 18 - 6 * g;
        v = (i >= 0 && i < 6) ? extW1[((p * 2 + g) * 6 + i) * 32 + o] : 0.f;
      } else {
        const int o = n - 64, i = d - 30;
        v = (i >= 0) ? oppW1[(p * 18 + i) * 32 + o] : 0.f;
      }
      o8[j] = f2bf(v);
    }
  } else if (t < TILE_PW1) {
    int s = t - TILE_ENCB;
    const int nt2 = s & 1; s >>= 1;
    const int br = s % 3; s /= 3;
    const int kt = s % 18; const int p = s / 18;
    const int n = kt * 32 + nt2 * 16 + lm;
    #pragma unroll
    for (int j = 0; j < 8; ++j) {
      const int k_pos = kbase + j;
      const int kperm = (k_pos & 1) * 16 + (k_pos >> 1);
      float v;
      if (br == 0)      { const int g = kt >> 1;   v = propW2[((p*9+g)*32 + k_pos)*64 + (n - g*64)]; }
      else if (br == 1) { const int g = (kt >= 9); v = extW2 [((p*2+g)*32 + kperm)*288 + (n - g*288)]; }
      else              {                          v = oppW2 [(p*32 + kperm)*576 + n]; }
      o8[j] = f2bf(v);
    }
  } else if (t < TILE_PW2) {
    int s = t - TILE_PW1;
    const int nt = s & 15; s >>= 4;
    const int kt = s % 18; const int p = s / 18;
    const int col = nt * 16 + lm;
    #pragma unroll
    for (int j = 0; j < 8; ++j) {
      const int k_pos = kbase + j;
      const int kperm = (k_pos & 1) * 16 + (k_pos >> 1);
      o8[j] = f2bf(piW1[(p * 576 + kt * 32 + kperm) * 256 + col]);
    }
  } else if (t < TILE_PW3) {
    int s = t - TILE_PW2;
    const int nt = s & 15; s >>= 4;
    const int kt = s & 7; const int p = s >> 3;
    const int col = nt * 16 + lm;
    #pragma unroll
    for (int j = 0; j < 8; ++j) {
      const int k_pos = kbase + j;
      const int kperm = (k_pos & 1) * 16 + (k_pos >> 1);
      o8[j] = f2bf(piW2[(p * 256 + kt * 32 + kperm) * 256 + col]);
    }
  } else {
    int s = t - TILE_PW3;
    const int kt = s & 7; const int p = s >> 3;
    #pragma unroll
    for (int j = 0; j < 8; ++j) {
      const int k_pos = kbase + j;
      const int kperm = (k_pos & 1) * 16 + (k_pos >> 1);
      o8[j] = (lm < 3) ? f2bf(piW3[(p * 256 + kt * 32 + kperm) * 3 + lm]) : (unsigned short)0;
    }
  }

  *(uint4*)&ws16[(size_t)u * 8] = *(const uint4*)o8;
}

// ---------------------------------------------------------------------------
__global__ __launch_bounds__(256, 4) void fused_kernel(
    const float* __restrict__ obs,
    const float* __restrict__ propW1, const float* __restrict__ propB1,
    const float* __restrict__ propB2,
    const float* __restrict__ extB1,  const float* __restrict__ extB2,
    const float* __restrict__ oppB1,  const float* __restrict__ oppB2,
    const unsigned short* __restrict__ wsAll,
    const float* __restrict__ b1v, const float* __restrict__ b2v,
    const float* __restrict__ b3v,
    float* __restrict__ out)
{
  __shared__ __align__(16) unsigned short smem[SM_TOT];  // 36864 B arena
  unsigned short* encb  = smem;            // stride 136 (enc phase)
  unsigned short* obs_s = smem + SM_OBS;   // stride 48  (dead after enc)
  unsigned short* Hsb   = smem + SM_HS;    // stride 104 (dead after enc)
  unsigned short* hbuf  = smem;            // stride 264 (h1/h2 phase)

  const unsigned short* b1aW = wsAll + OFF_B1A;
  const unsigned short* encB = wsAll + OFF_ENCB;
  const unsigned short* w1sw = wsAll + OFF_PW1;
  const unsigned short* w2sw = wsAll + OFF_PW2;
  const unsigned short* w3sw = wsAll + OFF_PW3;

  const int tid = threadIdx.x;
  const int p = blockIdx.y, brow = blockIdx.x;
  const int sbase = brow * 64;
  const int wv = tid >> 6, l = tid & 63, lm = l & 15, q = l >> 4;
  const f32x4 zz = {0.f, 0.f, 0.f, 0.f};

  // ---- phase 0: obs -> LDS bf16 ----
  {
    const int s = tid >> 2, c4 = tid & 3;
    if (c4 < 3) {
      const int c0 = c4 * 16;
      const float4* src = (const float4*)&obs[(sbase + s) * 144 + p * 48 + c0];
      float4 v0 = src[0], v1 = src[1], v2 = src[2], v3 = src[3];
      unsigned int pk[8];
      pk[0] = pk2bf(v0.x, v0.y); pk[1] = pk2bf(v0.z, v0.w);
      pk[2] = pk2bf(v1.x, v1.y); pk[3] = pk2bf(v1.z, v1.w);
      pk[4] = pk2bf(v2.x, v2.y); pk[5] = pk2bf(v2.z, v2.w);
      pk[6] = pk2bf(v3.x, v3.y); pk[7] = pk2bf(v3.z, v3.w);
      *(uint4*)&obs_s[s * OBS_STRIDE + c0]     = *(uint4*)&pk[0];
      *(uint4*)&obs_s[s * OBS_STRIDE + c0 + 8] = *(uint4*)&pk[4];
    }
  }
  __syncthreads();

  // ---- phase 1a: ext+opp layer-1 via MFMA (waves 1..3), bias in C ----
  if (wv >= 1) {
    const int go = wv - 1;                      // 0: ext0, 1: ext1, 2: opp
    bf16x8 af[4];
    #pragma unroll
    for (int ms = 0; ms < 4; ++ms)
      af[ms] = *(const bf16x8*)&obs_s[(ms * 16 + lm) * OBS_STRIDE + 16 + q * 8];
    bf16x8 bf0 = *(const bf16x8*)&b1aW[((p * 3 + go) * 2 + 0) * 512 + l * 8];
    bf16x8 bf1 = *(const bf16x8*)&b1aW[((p * 3 + go) * 2 + 1) * 512 + l * 8];
    float bias0, bias1;
    if (go < 2) { bias0 = extB1[(p*2+go)*32 + lm]; bias1 = extB1[(p*2+go)*32 + 16 + lm]; }
    else        { bias0 = oppB1[p*32 + lm];        bias1 = oppB1[p*32 + 16 + lm]; }
    const f32x4 cb0 = splat4(bias0), cb1 = splat4(bias1);
    #pragma unroll
    for (int ms = 0; ms < 4; ++ms) {
      f32x4 c0 = lrelu4(__builtin_amdgcn_mfma_f32_16x16x32_bf16(af[ms], bf0, cb0, 0, 0, 0));
      f32x4 c1 = lrelu4(__builtin_amdgcn_mfma_f32_16x16x32_bf16(af[ms], bf1, cb1, 0, 0, 0));
      #pragma unroll
      for (int r = 0; r < 4; ++r)
        *(unsigned int*)&Hsb[(ms * 16 + q * 4 + r) * HS_STRIDE + go * 32 + lm * 2] =
            pk2bf(c0[r], c1[r]);
    }
  }
  __syncthreads();

  // ---- pi L1 bias preload + acc init (bias in C) ----
  float b1r[4];
  #pragma unroll
  for (int nt = 0; nt < 4; ++nt) b1r[nt] = b1v[p * 256 + wv * 64 + nt * 16 + lm];
  f32x4 acc[4][4];
  #pragma unroll
  for (int a = 0; a < 4; ++a)
    #pragma unroll
    for (int b = 0; b < 4; ++b) acc[a][b] = splat4(b1r[b]);

  // ---- enc: 5 groups (4,4,4,4,2 kts), 1 kt/wave, + pi-L1 partials ----
  for (int g = 0; g < 5; ++g) {
    const int nk = (g < 4) ? 4 : 2;
    if (wv < nk) {
      const int kt = g * 4 + wv, ktloc = wv;
      const int gp = kt >> 1, ge = (kt >= 9) ? 1 : 0;

      // 1) prop-H A-frags first (prop weights die before W2 frags)
      bf16x8 apf[4];
      {
        f32x2 w0v[4], w1v[4], bbv[4];
        const float4* p4 = (const float4*)&propW1[(p * 9 + gp) * 64];
        float4 t0a = p4[q * 2],     t0b = p4[q * 2 + 1];
        float4 t1a = p4[8 + q * 2], t1b = p4[8 + q * 2 + 1];
        const float4* pb4 = (const float4*)&propB1[(p * 9 + gp) * 32];
        float4 tba = pb4[q * 2],    tbb = pb4[q * 2 + 1];
        w0v[0] = (f32x2){t0a.x, t0a.y}; w0v[1] = (f32x2){t0a.z, t0a.w};
        w0v[2] = (f32x2){t0b.x, t0b.y}; w0v[3] = (f32x2){t0b.z, t0b.w};
        w1v[0] = (f32x2){t1a.x, t1a.y}; w1v[1] = (f32x2){t1a.z, t1a.w};
        w1v[2] = (f32x2){t1b.x, t1b.y}; w1v[3] = (f32x2){t1b.z, t1b.w};
        bbv[0] = (f32x2){tba.x, tba.y}; bbv[1] = (f32x2){tba.z, tba.w};
        bbv[2] = (f32x2){tbb.x, tbb.y}; bbv[3] = (f32x2){tbb.z, tbb.w};
        #pragma unroll
        for (int ms = 0; ms < 4; ++ms) {
          const int row = ms * 16 + lm;
          const unsigned int xu = *(const unsigned int*)&obs_s[row * OBS_STRIDE + 2 * gp];
          const f32x2 x0v = {u2f(xu << 16), u2f(xu << 16)};
          const f32x2 x1v = {u2f(xu & 0xffff0000u), u2f(xu & 0xffff0000u)};
          unsigned int au[4];
          #pragma unroll
          for (int jj = 0; jj < 4; ++jj) {
            f32x2 h = bbv[jj] + x0v * w0v[jj] + x1v * w1v[jj];
            h = __builtin_elementwise_max(h, h * NEG_SLOPE);
            au[jj] = pk2bf(h.x, h.y);
          }
          __builtin_memcpy(&apf[ms], au, 16);
        }
      }

      // 2) W2 B-frags + scalar branch biases
      const int ebase = (p * 18 + kt) * 6;
      bf16x8 wpf[2], wef[2], wof[2];
      float bp[2], be[2], bo[2];
      #pragma unroll
      for (int nt2 = 0; nt2 < 2; ++nt2) {
        wpf[nt2] = *(const bf16x8*)&encB[(ebase + nt2) * 512 + l * 8];
        wef[nt2] = *(const bf16x8*)&encB[(ebase + 2 + nt2) * 512 + l * 8];
        wof[nt2] = *(const bf16x8*)&encB[(ebase + 4 + nt2) * 512 + l * 8];
        const int nc = nt2 * 16 + lm;
        bp[nt2] = propB2[(p * 9 + gp) * 64 + (kt & 1) * 32 + nc];
        be[nt2] = extB2[(p * 2 + ge) * 288 + (kt - ge * 9) * 32 + nc];
        bo[nt2] = oppB2[p * 576 + kt * 32 + nc];
      }

      // 3) MFMAs sequenced per nt2, packed epilogue
      #pragma unroll
      for (int ms = 0; ms < 4; ++ms) {
        const int row = ms * 16 + lm;
        bf16x8 ae = *(const bf16x8*)&Hsb[row * HS_STRIDE + ge * 32 + q * 8];
        bf16x8 ao = *(const bf16x8*)&Hsb[row * HS_STRIDE + 64 + q * 8];
        f32x4 s0, s1;
        {
          f32x4 cp = __builtin_amdgcn_mfma_f32_16x16x32_bf16(apf[ms], wpf[0], zz, 0, 0, 0);
          f32x4 ce = __builtin_amdgcn_mfma_f32_16x16x32_bf16(ae,      wef[0], zz, 0, 0, 0);
          f32x4 co = __builtin_amdgcn_mfma_f32_16x16x32_bf16(ao,      wof[0], zz, 0, 0, 0);
          s0 = lrelu4(cp + splat4(bp[0])) + lrelu4(ce + splat4(be[0])) + lrelu4(co + splat4(bo[0]));
        }
        {
          f32x4 cp = __builtin_amdgcn_mfma_f32_16x16x32_bf16(apf[ms], wpf[1], zz, 0, 0, 0);
          f32x4 ce = __builtin_amdgcn_mfma_f32_16x16x32_bf16(ae,      wef[1], zz, 0, 0, 0);
          f32x4 co = __builtin_amdgcn_mfma_f32_16x16x32_bf16(ao,      wof[1], zz, 0, 0, 0);
          s1 = lrelu4(cp + splat4(bp[1])) + lrelu4(ce + splat4(be[1])) + lrelu4(co + splat4(bo[1]));
        }
        #pragma unroll
        for (int r = 0; r < 4; ++r)
          *(unsigned int*)&encb[(ms * 16 + q * 4 + r) * ENC_STRIDE + ktloc * 32 + lm * 2] =
              pk2bf(s0[r], s1[r]);
      }
    }
    __syncthreads();

    // --- pi L1 partial over this group's k-tiles (all 4 waves) ---
    for (int ktloc = 0; ktloc < nk; ++ktloc) {
      const int kt = g * 4 + ktloc;
      bf16x8 afr[4], bfr[4];
      #pragma unroll
      for (int ms = 0; ms < 4; ++ms)
        afr[ms] = *(const bf16x8*)&encb[(ms * 16 + lm) * ENC_STRIDE + ktloc * 32 + q * 8];
      const int wb = ((p * 18 + kt) * 16 + wv * 4) * 512 + l * 8;
      #pragma unroll
      for (int nt = 0; nt < 4; ++nt)
        bfr[nt] = *(const bf16x8*)&w1sw[wb + nt * 512];
      #pragma unroll
      for (int ms = 0; ms < 4; ++ms)
        #pragma unroll
        for (int nt = 0; nt < 4; ++nt)
          acc[ms][nt] = __builtin_amdgcn_mfma_f32_16x16x32_bf16(afr[ms], bfr[nt], acc[ms][nt], 0, 0, 0);
    }
    __syncthreads();
  }

  // ---- h1 epilogue (packed lrelu, pair-packed; overwrites obs/Hs: dead) ----
  #pragma unroll
  for (int ms = 0; ms < 4; ++ms)
    #pragma unroll
    for (int pi2 = 0; pi2 < 2; ++pi2) {
      f32x4 a0 = lrelu4(acc[ms][pi2 * 2]);
      f32x4 a1 = lrelu4(acc[ms][pi2 * 2 + 1]);
      #pragma unroll
      for (int r = 0; r < 4; ++r)
        *(unsigned int*)&hbuf[(ms * 16 + q * 4 + r) * H_STRIDE + (wv * 2 + pi2) * 32 + lm * 2] =
            pk2bf(a0[r], a1[r]);
    }
  __syncthreads();

  // ---- pi L2: 256 -> 256 (bias in C) ----
  {
    float b2r[4];
    #pragma unroll
    for (int nt = 0; nt < 4; ++nt) b2r[nt] = b2v[p * 256 + wv * 64 + nt * 16 + lm];
    #pragma unroll
    for (int a = 0; a < 4; ++a)
      #pragma unroll
      for (int b = 0; b < 4; ++b) acc[a][b] = splat4(b2r[b]);
  }
  for (int kt = 0; kt < 8; ++kt) {
    bf16x8 afr[4], bfr[4];
    #pragma unroll
    for (int ms = 0; ms < 4; ++ms)
      afr[ms] = *(const bf16x8*)&hbuf[(ms * 16 + lm) * H_STRIDE + kt * 32 + q * 8];
    const int wb = ((p * 8 + kt) * 16 + wv * 4) * 512 + l * 8;
    #pragma unroll
    for (int nt = 0; nt < 4; ++nt)
      bfr[nt] = *(const bf16x8*)&w2sw[wb + nt * 512];
    #pragma unroll
    for (int ms = 0; ms < 4; ++ms)
      #pragma unroll
      for (int nt = 0; nt < 4; ++nt)
        acc[ms][nt] = __builtin_amdgcn_mfma_f32_16x16x32_bf16(afr[ms], bfr[nt], acc[ms][nt], 0, 0, 0);
  }
  __syncthreads();                 // all h1 reads complete before overwrite
  #pragma unroll
  for (int ms = 0; ms < 4; ++ms)
    #pragma unroll
    for (int pi2 = 0; pi2 < 2; ++pi2) {
      f32x4 a0 = lrelu4(acc[ms][pi2 * 2]);
      f32x4 a1 = lrelu4(acc[ms][pi2 * 2 + 1]);
      #pragma unroll
      for (int r = 0; r < 4; ++r)
        *(unsigned int*)&hbuf[(ms * 16 + q * 4 + r) * H_STRIDE + (wv * 2 + pi2) * 32 + lm * 2] =
            pk2bf(a0[r], a1[r]);
    }
  __syncthreads();

  // ---- pi L3: 256 -> 3 (N padded to 16) + tanh, bias in C ----
  const float bias3 = (lm < 3) ? b3v[p * 3 + lm] : 0.f;
  f32x4 a3 = splat4(bias3);
  for (int kt = 0; kt < 8; ++kt) {
    bf16x8 afr = *(const bf16x8*)&hbuf[(wv * 16 + lm) * H_STRIDE + kt * 32 + q * 8];
    bf16x8 bfr = *(const bf16x8*)&w3sw[((p * 8 + kt) * 64 + l) * 8];
    a3 = __builtin_amdgcn_mfma_f32_16x16x32_bf16(afr, bfr, a3, 0, 0, 0);
  }
  if (lm < 3) {
    #pragma unroll
    for (int r = 0; r < 4; ++r) {
      const int s = wv * 16 + q * 4 + r;
      out[(sbase + s) * 9 + p * 3 + lm] = fast_tanh(a3[r]);
    }
  }
}

// ---------------------------------------------------------------------------
extern "C" void kernel_launch(void* const* d_in, const int* in_sizes, int n_in,
                              void* d_out, int out_size, void* d_ws, size_t ws_size,
                              hipStream_t stream)
{
  (void)in_sizes; (void)n_in; (void)out_size; (void)ws_size;
  const float* obs    = (const float*)d_in[0];
  const float* propW1 = (const float*)d_in[1];
  const float* propB1 = (const float*)d_in[2];
  const float* propW2 = (const float*)d_in[3];
  const float* propB2 = (const float*)d_in[4];
  const float* extW1  = (const float*)d_in[5];
  const float* extB1  = (const float*)d_in[6];
  const float* extW2  = (const float*)d_in[7];
  const float* extB2  = (const float*)d_in[8];
  const float* oppW1  = (const float*)d_in[9];
  const float* oppB1  = (const float*)d_in[10];
  const float* oppW2  = (const float*)d_in[11];
  const float* oppB2  = (const float*)d_in[12];
  const float* piW1   = (const float*)d_in[13];
  const float* piB1   = (const float*)d_in[14];
  const float* piW2   = (const float*)d_in[15];
  const float* piB2   = (const float*)d_in[16];
  const float* piW3   = (const float*)d_in[17];
  const float* piB3   = (const float*)d_in[18];
  float* out = (float*)d_out;
  unsigned short* ws16 = (unsigned short*)d_ws;

  prep_kernel<<<dim3(((WS_TOTAL >> 3) + 255) / 256), dim3(256), 0, stream>>>(
      propW2, extW1, extW2, oppW1, oppW2, piW1, piW2, piW3, ws16);

  fused_kernel<<<dim3(65536 / 64, 3), dim3(256), 0, stream>>>(
      obs, propW1, propB1, propB2, extB1, extB2, oppB1, oppB2,
      ws16, piB1, piB2, piB3, out);
}

// Round 10
// 263.559 us; speedup vs baseline: 1.1647x; 1.1647x over previous
//
#include <hip/hip_runtime.h>
#include <math.h>

// ---------------------------------------------------------------------------
// MLPAC_4_team fused v10: B=65536, P=3.
// v6 -> v10: enc production double-buffered (groups of 4 kt, 2 LDS bufs):
// per iteration each wave does produce(g+1) then consume(g) with ONE barrier,
// letting produce-VALU co-issue with consume-MFMA. LDS 54,272 B, still
// 3 blocks/CU at __launch_bounds__(256,3) — the only no-spill config
// (register model: 64 AGPR acc + ~84 VGPR = 148; caps 170/128/85 explain
// R4/R7/R8/R9 spills). Fast exp-based tanh. prep unchanged from v6.
// ---------------------------------------------------------------------------

#define NEG_SLOPE 0.01f

// ws offsets in ushort elements
#define OFF_B1A  0
#define OFF_ENCB 9216
#define OFF_PW1  175104
#define OFF_PW2  617472
#define OFF_PW3  814080
#define WS_TOTAL 826368

// tile (512-short) boundaries
#define TILE_ENCB 18
#define TILE_PW1  342
#define TILE_PW2  1206
#define TILE_PW3  1590

#define OBS_STRIDE 48     // shorts/row
#define HS_STRIDE  104    // shorts/row (96 used: ext0|ext1|opp)
#define ENC_STRIDE 136    // shorts/row (4*32 used + 8 pad)
#define H_STRIDE   264    // shorts/row (256 used)

// smem arena (shorts): buf0 | buf1 | obs | Hs ; hbuf overlays buf0+buf1
#define SM_BUF1 8704
#define SM_OBS  17408
#define SM_HS   20480
#define SM_TOT  27136     // 54272 B -> 3 blocks/CU (3*54272=162816<=163840)

typedef short bf16x8 __attribute__((ext_vector_type(8)));
typedef float f32x4  __attribute__((ext_vector_type(4)));
typedef float f32x2  __attribute__((ext_vector_type(2)));

__device__ __forceinline__ float lrelu(float x) { return fmaxf(x, NEG_SLOPE * x); }

__device__ __forceinline__ f32x4 lrelu4(f32x4 x) {
  return __builtin_elementwise_max(x, x * NEG_SLOPE);
}
__device__ __forceinline__ f32x4 splat4(float b) { return (f32x4){b, b, b, b}; }

__device__ __forceinline__ float u2f(unsigned int u) {
  union { unsigned int u; float f; } c; c.u = u; return c.f;
}

__device__ __forceinline__ float fast_tanh(float x) {
  x = fminf(10.f, fmaxf(-10.f, x));
  float e = __expf(2.f * x);
  return (e - 1.f) * __frcp_rn(e + 1.f);
}

// pack two f32 -> two bf16 (round-half-up) in one v_perm_b32
__device__ __forceinline__ unsigned int pk2bf(float a, float b) {
  union { float f; unsigned int u; } ca, cb; ca.f = a; cb.f = b;
  return __builtin_amdgcn_perm(cb.u + 0x8000u, ca.u + 0x8000u, 0x07060302u);
}

__device__ __forceinline__ unsigned short f2bf(float x) {  // RNE, prep only
  union { float f; unsigned int u; } c; c.f = x;
  unsigned int u = (c.u + 0x7fffu + ((c.u >> 16) & 1u)) >> 16;
  return (unsigned short)u;
}

// ---------------------------------------------------------------------------
// prep (v6): one thread = one frag row (lane) = 8 shorts = one uint4 store.
// B-frag layout: lane l holds B[k_pos=(l>>4)*8+j][n=l&15], j=0..7.
// kperm = (k_pos&1)*16 + (k_pos>>1) absorbs the pair-pack column permutation.
// ---------------------------------------------------------------------------
__global__ __launch_bounds__(256) void prep_kernel(
    const float* __restrict__ propW2, const float* __restrict__ extW1,
    const float* __restrict__ extW2,  const float* __restrict__ oppW1,
    const float* __restrict__ oppW2,  const float* __restrict__ piW1,
    const float* __restrict__ piW2,   const float* __restrict__ piW3,
    unsigned short* __restrict__ ws16)
{
  const int u = blockIdx.x * 256 + threadIdx.x;   // frag-row index
  if (u >= (WS_TOTAL >> 3)) return;
  const int lane = u & 63;
  const int t = u >> 6;                            // 512-short tile index
  const int lm = lane & 15;
  const int kbase = (lane >> 4) << 3;              // k_pos = kbase + j

  unsigned short o8[8];

  if (t < TILE_ENCB) {
    int s = t;
    const int nt2 = s & 1; s >>= 1;
    const int go = s % 3; const int p = s / 3;
    const int n = go * 32 + nt2 * 16 + lm;
    #pragma unroll
    for (int j = 0; j < 8; ++j) {
      const int d = 16 + kbase + j;
      float v;
      if (n < 64) {
        const int g = n >> 5, o = n & 31, i = d - 18 - 6 * g;
        v = (i >= 0 && i < 6) ? extW1[((p * 2 + g) * 6 + i) * 32 + o] : 0.f;
      } else {
        const int o = n - 64, i = d - 30;
        v = (i >= 0) ? oppW1[(p * 18 + i) * 32 + o] : 0.f;
      }
      o8[j] = f2bf(v);
    }
  } else if (t < TILE_PW1) {
    int s = t - TILE_ENCB;
    const int nt2 = s & 1; s >>= 1;
    const int br = s % 3; s /= 3;
    const int kt = s % 18; const int p = s / 18;
    const int n = kt * 32 + nt2 * 16 + lm;
    #pragma unroll
    for (int j = 0; j < 8; ++j) {
      const int k_pos = kbase + j;
      const int kperm = (k_pos & 1) * 16 + (k_pos >> 1);
      float v;
      if (br == 0)      { const int g = kt >> 1;   v = propW2[((p*9+g)*32 + k_pos)*64 + (n - g*64)]; }
      else if (br == 1) { const int g = (kt >= 9); v = extW2 [((p*2+g)*32 + kperm)*288 + (n - g*288)]; }
      else              {                          v = oppW2 [(p*32 + kperm)*576 + n]; }
      o8[j] = f2bf(v);
    }
  } else if (t < TILE_PW2) {
    int s = t - TILE_PW1;
    const int nt = s & 15; s >>= 4;
    const int kt = s % 18; const int p = s / 18;
    const int col = nt * 16 + lm;
    #pragma unroll
    for (int j = 0; j < 8; ++j) {
      const int k_pos = kbase + j;
      const int kperm = (k_pos & 1) * 16 + (k_pos >> 1);
      o8[j] = f2bf(piW1[(p * 576 + kt * 32 + kperm) * 256 + col]);
    }
  } else if (t < TILE_PW3) {
    int s = t - TILE_PW2;
    const int nt = s & 15; s >>= 4;
    const int kt = s & 7; const int p = s >> 3;
    const int col = nt * 16 + lm;
    #pragma unroll
    for (int j = 0; j < 8; ++j) {
      const int k_pos = kbase + j;
      const int kperm = (k_pos & 1) * 16 + (k_pos >> 1);
      o8[j] = f2bf(piW2[(p * 256 + kt * 32 + kperm) * 256 + col]);
    }
  } else {
    int s = t - TILE_PW3;
    const int kt = s & 7; const int p = s >> 3;
    #pragma unroll
    for (int j = 0; j < 8; ++j) {
      const int k_pos = kbase + j;
      const int kperm = (k_pos & 1) * 16 + (k_pos >> 1);
      o8[j] = (lm < 3) ? f2bf(piW3[(p * 256 + kt * 32 + kperm) * 3 + lm]) : (unsigned short)0;
    }
  }

  *(uint4*)&ws16[(size_t)u * 8] = *(const uint4*)o8;
}

// ---------------------------------------------------------------------------
__global__ __launch_bounds__(256, 3) void fused_kernel(
    const float* __restrict__ obs,
    const float* __restrict__ propW1, const float* __restrict__ propB1,
    const float* __restrict__ propB2,
    const float* __restrict__ extB1,  const float* __restrict__ extB2,
    const float* __restrict__ oppB1,  const float* __restrict__ oppB2,
    const unsigned short* __restrict__ wsAll,
    const float* __restrict__ b1v, const float* __restrict__ b2v,
    const float* __restrict__ b3v,
    float* __restrict__ out)
{
  __shared__ __align__(16) unsigned short smem[SM_TOT];  // 54272 B arena
  unsigned short* obs_s = smem + SM_OBS;   // stride 48  (dead after enc)
  unsigned short* Hsb   = smem + SM_HS;    // stride 104 (dead after enc)
  unsigned short* hbuf  = smem;            // stride 264 (h1/h2 phase, overlays bufs)

  const unsigned short* b1aW = wsAll + OFF_B1A;
  const unsigned short* encB = wsAll + OFF_ENCB;
  const unsigned short* w1sw = wsAll + OFF_PW1;
  const unsigned short* w2sw = wsAll + OFF_PW2;
  const unsigned short* w3sw = wsAll + OFF_PW3;

  const int tid = threadIdx.x;
  const int p = blockIdx.y, brow = blockIdx.x;
  const int sbase = brow * 64;
  const int wv = tid >> 6, l = tid & 63, lm = l & 15, q = l >> 4;
  const f32x4 zz = {0.f, 0.f, 0.f, 0.f};

  // ---- phase 0: obs -> LDS bf16 ----
  {
    const int s = tid >> 2, c4 = tid & 3;
    if (c4 < 3) {
      const int c0 = c4 * 16;
      const float4* src = (const float4*)&obs[(sbase + s) * 144 + p * 48 + c0];
      float4 v0 = src[0], v1 = src[1], v2 = src[2], v3 = src[3];
      unsigned int pk[8];
      pk[0] = pk2bf(v0.x, v0.y); pk[1] = pk2bf(v0.z, v0.w);
      pk[2] = pk2bf(v1.x, v1.y); pk[3] = pk2bf(v1.z, v1.w);
      pk[4] = pk2bf(v2.x, v2.y); pk[5] = pk2bf(v2.z, v2.w);
      pk[6] = pk2bf(v3.x, v3.y); pk[7] = pk2bf(v3.z, v3.w);
      *(uint4*)&obs_s[s * OBS_STRIDE + c0]     = *(uint4*)&pk[0];
      *(uint4*)&obs_s[s * OBS_STRIDE + c0 + 8] = *(uint4*)&pk[4];
    }
  }
  __syncthreads();

  // ---- phase 1a: ext+opp layer-1 via MFMA (waves 1..3), bias in C ----
  if (wv >= 1) {
    const int go = wv - 1;                      // 0: ext0, 1: ext1, 2: opp
    bf16x8 af[4];
    #pragma unroll
    for (int ms = 0; ms < 4; ++ms)
      af[ms] = *(const bf16x8*)&obs_s[(ms * 16 + lm) * OBS_STRIDE + 16 + q * 8];
    bf16x8 bf0 = *(const bf16x8*)&b1aW[((p * 3 + go) * 2 + 0) * 512 + l * 8];
    bf16x8 bf1 = *(const bf16x8*)&b1aW[((p * 3 + go) * 2 + 1) * 512 + l * 8];
    float bias0, bias1;
    if (go < 2) { bias0 = extB1[(p*2+go)*32 + lm]; bias1 = extB1[(p*2+go)*32 + 16 + lm]; }
    else        { bias0 = oppB1[p*32 + lm];        bias1 = oppB1[p*32 + 16 + lm]; }
    const f32x4 cb0 = splat4(bias0), cb1 = splat4(bias1);
    #pragma unroll
    for (int ms = 0; ms < 4; ++ms) {
      f32x4 c0 = lrelu4(__builtin_amdgcn_mfma_f32_16x16x32_bf16(af[ms], bf0, cb0, 0, 0, 0));
      f32x4 c1 = lrelu4(__builtin_amdgcn_mfma_f32_16x16x32_bf16(af[ms], bf1, cb1, 0, 0, 0));
      #pragma unroll
      for (int r = 0; r < 4; ++r)
        *(unsigned int*)&Hsb[(ms * 16 + q * 4 + r) * HS_STRIDE + go * 32 + lm * 2] =
            pk2bf(c0[r], c1[r]);
    }
  }

  // ---- pi L1 bias preload + acc init (bias in C) ----
  float b1r[4];
  #pragma unroll
  for (int nt = 0; nt < 4; ++nt) b1r[nt] = b1v[p * 256 + wv * 64 + nt * 16 + lm];
  f32x4 acc[4][4];
  #pragma unroll
  for (int a = 0; a < 4; ++a)
    #pragma unroll
    for (int b = 0; b < 4; ++b) acc[a][b] = splat4(b1r[b]);

  // enc producer: wave wv builds kt = g*4+wv into buf[g&1] (if active)
  auto produce = [&](int g) {
    const int nk = (g < 4) ? 4 : 2;
    if (wv >= nk) return;
    unsigned short* buf = smem + (g & 1) * SM_BUF1;
    const int kt = g * 4 + wv, ktloc = wv;
    const int gp = kt >> 1, ge = (kt >= 9) ? 1 : 0;

    // 1) prop-H A-frags first (prop weights die before W2 frags)
    bf16x8 apf[4];
    {
      f32x2 w0v[4], w1v[4], bbv[4];
      const float4* p4 = (const float4*)&propW1[(p * 9 + gp) * 64];
      float4 t0a = p4[q * 2],     t0b = p4[q * 2 + 1];
      float4 t1a = p4[8 + q * 2], t1b = p4[8 + q * 2 + 1];
      const float4* pb4 = (const float4*)&propB1[(p * 9 + gp) * 32];
      float4 tba = pb4[q * 2],    tbb = pb4[q * 2 + 1];
      w0v[0] = (f32x2){t0a.x, t0a.y}; w0v[1] = (f32x2){t0a.z, t0a.w};
      w0v[2] = (f32x2){t0b.x, t0b.y}; w0v[3] = (f32x2){t0b.z, t0b.w};
      w1v[0] = (f32x2){t1a.x, t1a.y}; w1v[1] = (f32x2){t1a.z, t1a.w};
      w1v[2] = (f32x2){t1b.x, t1b.y}; w1v[3] = (f32x2){t1b.z, t1b.w};
      bbv[0] = (f32x2){tba.x, tba.y}; bbv[1] = (f32x2){tba.z, tba.w};
      bbv[2] = (f32x2){tbb.x, tbb.y}; bbv[3] = (f32x2){tbb.z, tbb.w};
      #pragma unroll
      for (int ms = 0; ms < 4; ++ms) {
        const int row = ms * 16 + lm;
        const unsigned int xu = *(const unsigned int*)&obs_s[row * OBS_STRIDE + 2 * gp];
        const f32x2 x0v = {u2f(xu << 16), u2f(xu << 16)};
        const f32x2 x1v = {u2f(xu & 0xffff0000u), u2f(xu & 0xffff0000u)};
        unsigned int au[4];
        #pragma unroll
        for (int jj = 0; jj < 4; ++jj) {
          f32x2 h = bbv[jj] + x0v * w0v[jj] + x1v * w1v[jj];
          h = __builtin_elementwise_max(h, h * NEG_SLOPE);
          au[jj] = pk2bf(h.x, h.y);
        }
        __builtin_memcpy(&apf[ms], au, 16);
      }
    }

    // 2) W2 B-frags + scalar branch biases
    const int ebase = (p * 18 + kt) * 6;
    bf16x8 wpf[2], wef[2], wof[2];
    float bp[2], be[2], bo[2];
    #pragma unroll
    for (int nt2 = 0; nt2 < 2; ++nt2) {
      wpf[nt2] = *(const bf16x8*)&encB[(ebase + nt2) * 512 + l * 8];
      wef[nt2] = *(const bf16x8*)&encB[(ebase + 2 + nt2) * 512 + l * 8];
      wof[nt2] = *(const bf16x8*)&encB[(ebase + 4 + nt2) * 512 + l * 8];
      const int nc = nt2 * 16 + lm;
      bp[nt2] = propB2[(p * 9 + gp) * 64 + (kt & 1) * 32 + nc];
      be[nt2] = extB2[(p * 2 + ge) * 288 + (kt - ge * 9) * 32 + nc];
      bo[nt2] = oppB2[p * 576 + kt * 32 + nc];
    }

    // 3) MFMAs sequenced per nt2, packed epilogue
    #pragma unroll
    for (int ms = 0; ms < 4; ++ms) {
      const int row = ms * 16 + lm;
      bf16x8 ae = *(const bf16x8*)&Hsb[row * HS_STRIDE + ge * 32 + q * 8];
      bf16x8 ao = *(const bf16x8*)&Hsb[row * HS_STRIDE + 64 + q * 8];
      f32x4 s0, s1;
      {
        f32x4 cp = __builtin_amdgcn_mfma_f32_16x16x32_bf16(apf[ms], wpf[0], zz, 0, 0, 0);
        f32x4 ce = __builtin_amdgcn_mfma_f32_16x16x32_bf16(ae,      wef[0], zz, 0, 0, 0);
        f32x4 co = __builtin_amdgcn_mfma_f32_16x16x32_bf16(ao,      wof[0], zz, 0, 0, 0);
        s0 = lrelu4(cp + splat4(bp[0])) + lrelu4(ce + splat4(be[0])) + lrelu4(co + splat4(bo[0]));
      }
      {
        f32x4 cp = __builtin_amdgcn_mfma_f32_16x16x32_bf16(apf[ms], wpf[1], zz, 0, 0, 0);
        f32x4 ce = __builtin_amdgcn_mfma_f32_16x16x32_bf16(ae,      wef[1], zz, 0, 0, 0);
        f32x4 co = __builtin_amdgcn_mfma_f32_16x16x32_bf16(ao,      wof[1], zz, 0, 0, 0);
        s1 = lrelu4(cp + splat4(bp[1])) + lrelu4(ce + splat4(be[1])) + lrelu4(co + splat4(bo[1]));
      }
      #pragma unroll
      for (int r = 0; r < 4; ++r)
        *(unsigned int*)&buf[(ms * 16 + q * 4 + r) * ENC_STRIDE + ktloc * 32 + lm * 2] =
            pk2bf(s0[r], s1[r]);
    }
  };

  // ---- software pipeline: produce(0); then {produce(g+1); consume(g)} ----
  __syncthreads();            // Hs (phase 1a) visible
  produce(0);
  __syncthreads();            // buf0 ready

  for (int g = 0; g < 5; ++g) {
    if (g < 4) produce(g + 1);               // writes buf[(g+1)&1]

    // consume(g): pi L1 partial from buf[g&1]  (overlaps produce via scheduler)
    const unsigned short* buf = smem + (g & 1) * SM_BUF1;
    const int nk = (g < 4) ? 4 : 2;
    for (int ktloc = 0; ktloc < nk; ++ktloc) {
      const int kt = g * 4 + ktloc;
      bf16x8 afr[4], bfr[4];
      #pragma unroll
      for (int ms = 0; ms < 4; ++ms)
        afr[ms] = *(const bf16x8*)&buf[(ms * 16 + lm) * ENC_STRIDE + ktloc * 32 + q * 8];
      const int wb = ((p * 18 + kt) * 16 + wv * 4) * 512 + l * 8;
      #pragma unroll
      for (int nt = 0; nt < 4; ++nt)
        bfr[nt] = *(const bf16x8*)&w1sw[wb + nt * 512];
      #pragma unroll
      for (int ms = 0; ms < 4; ++ms)
        #pragma unroll
        for (int nt = 0; nt < 4; ++nt)
          acc[ms][nt] = __builtin_amdgcn_mfma_f32_16x16x32_bf16(afr[ms], bfr[nt], acc[ms][nt], 0, 0, 0);
    }
    __syncthreads();   // produce(g+1) done for all waves; consume(g) reads done
  }

  // ---- h1 epilogue (packed lrelu; overwrites enc bufs: dead) ----
  #pragma unroll
  for (int ms = 0; ms < 4; ++ms)
    #pragma unroll
    for (int pi2 = 0; pi2 < 2; ++pi2) {
      f32x4 a0 = lrelu4(acc[ms][pi2 * 2]);
      f32x4 a1 = lrelu4(acc[ms][pi2 * 2 + 1]);
      #pragma unroll
      for (int r = 0; r < 4; ++r)
        *(unsigned int*)&hbuf[(ms * 16 + q * 4 + r) * H_STRIDE + (wv * 2 + pi2) * 32 + lm * 2] =
            pk2bf(a0[r], a1[r]);
    }
  __syncthreads();

  // ---- pi L2: 256 -> 256 (bias in C) ----
  {
    float b2r[4];
    #pragma unroll
    for (int nt = 0; nt < 4; ++nt) b2r[nt] = b2v[p * 256 + wv * 64 + nt * 16 + lm];
    #pragma unroll
    for (int a = 0; a < 4; ++a)
      #pragma unroll
      for (int b = 0; b < 4; ++b) acc[a][b] = splat4(b2r[b]);
  }
  for (int kt = 0; kt < 8; ++kt) {
    bf16x8 afr[4], bfr[4];
    #pragma unroll
    for (int ms = 0; ms < 4; ++ms)
      afr[ms] = *(const bf16x8*)&hbuf[(ms * 16 + lm) * H_STRIDE + kt * 32 + q * 8];
    const int wb = ((p * 8 + kt) * 16 + wv * 4) * 512 + l * 8;
    #pragma unroll
    for (int nt = 0; nt < 4; ++nt)
      bfr[nt] = *(const bf16x8*)&w2sw[wb + nt * 512];
    #pragma unroll
    for (int ms = 0; ms < 4; ++ms)
      #pragma unroll
      for (int nt = 0; nt < 4; ++nt)
        acc[ms][nt] = __builtin_amdgcn_mfma_f32_16x16x32_bf16(afr[ms], bfr[nt], acc[ms][nt], 0, 0, 0);
  }
  __syncthreads();                 // all h1 reads complete before overwrite
  #pragma unroll
  for (int ms = 0; ms < 4; ++ms)
    #pragma unroll
    for (int pi2 = 0; pi2 < 2; ++pi2) {
      f32x4 a0 = lrelu4(acc[ms][pi2 * 2]);
      f32x4 a1 = lrelu4(acc[ms][pi2 * 2 + 1]);
      #pragma unroll
      for (int r = 0; r < 4; ++r)
        *(unsigned int*)&hbuf[(ms * 16 + q * 4 + r) * H_STRIDE + (wv * 2 + pi2) * 32 + lm * 2] =
            pk2bf(a0[r], a1[r]);
    }
  __syncthreads();

  // ---- pi L3: 256 -> 3 (N padded to 16) + tanh, bias in C ----
  const float bias3 = (lm < 3) ? b3v[p * 3 + lm] : 0.f;
  f32x4 a3 = splat4(bias3);
  for (int kt = 0; kt < 8; ++kt) {
    bf16x8 afr = *(const bf16x8*)&hbuf[(wv * 16 + lm) * H_STRIDE + kt * 32 + q * 8];
    bf16x8 bfr = *(const bf16x8*)&w3sw[((p * 8 + kt) * 64 + l) * 8];
    a3 = __builtin_amdgcn_mfma_f32_16x16x32_bf16(afr, bfr, a3, 0, 0, 0);
  }
  if (lm < 3) {
    #pragma unroll
    for (int r = 0; r < 4; ++r) {
      const int s = wv * 16 + q * 4 + r;
      out[(sbase + s) * 9 + p * 3 + lm] = fast_tanh(a3[r]);
    }
  }
}

// ---------------------------------------------------------------------------
extern "C" void kernel_launch(void* const* d_in, const int* in_sizes, int n_in,
                              void* d_out, int out_size, void* d_ws, size_t ws_size,
                              hipStream_t stream)
{
  (void)in_sizes; (void)n_in; (void)out_size; (void)ws_size;
  const float* obs    = (const float*)d_in[0];
  const float* propW1 = (const float*)d_in[1];
  const float* propB1 = (const float*)d_in[2];
  const float* propW2 = (const float*)d_in[3];
  const float* propB2 = (const float*)d_in[4];
  const float* extW1  = (const float*)d_in[5];
  const float* extB1  = (const float*)d_in[6];
  const float* extW2  = (const float*)d_in[7];
  const float* extB2  = (const float*)d_in[8];
  const float* oppW1  = (const float*)d_in[9];
  const float* oppB1  = (const float*)d_in[10];
  const float* oppW2  = (const float*)d_in[11];
  const float* oppB2  = (const float*)d_in[12];
  const float* piW1   = (const float*)d_in[13];
  const float* piB1   = (const float*)d_in[14];
  const float* piW2   = (const float*)d_in[15];
  const float* piB2   = (const float*)d_in[16];
  const float* piW3   = (const float*)d_in[17];
  const float* piB3   = (const float*)d_in[18];
  float* out = (float*)d_out;
  unsigned short* ws16 = (unsigned short*)d_ws;

  prep_kernel<<<dim3(((WS_TOTAL >> 3) + 255) / 256), dim3(256), 0, stream>>>(
      propW2, extW1, extW2, oppW1, oppW2, piW1, piW2, piW3, ws16);

  fused_kernel<<<dim3(65536 / 64, 3), dim3(256), 0, stream>>>(
      obs, propW1, propB1, propB2, extB1, extB2, oppB1, oppB2,
      ws16, piB1, piB2, piB3, out);
}

// Round 11
// 243.541 us; speedup vs baseline: 1.2604x; 1.0822x over previous
//
#include <hip/hip_runtime.h>
#include <math.h>

// ---------------------------------------------------------------------------
// MLPAC_4_team fused v11: B=65536, P=3.
// v10 -> v11: LDS arena shrunk 54,272 -> 51,200 B. R10 discovered LDS
// allocation granularity is 4 KiB (54,272 -> 57,344 alloc; x3 > 160 KiB ->
// 2 blocks/CU). 51,200 rounds to 53,248 -> 3 blocks/CU restored, keeping the
// double-buffered produce/consume pipeline. obs split: obs_prop[64][24]
// (cols 0..17, lives through enc) + obs_hi[64][32] (cols 16..47, phase-1a
// only, overlaid into buf1 which is first written by produce(1)).
// Register model (validated R4/R7/R8/R9/R10): 64 AGPR acc + ~84 VGPR;
// (256,3) cap=170 is the only no-spill occupancy. prep unchanged from v6.
// ---------------------------------------------------------------------------

#define NEG_SLOPE 0.01f

// ws offsets in ushort elements
#define OFF_B1A  0
#define OFF_ENCB 9216
#define OFF_PW1  175104
#define OFF_PW2  617472
#define OFF_PW3  814080
#define WS_TOTAL 826368

// tile (512-short) boundaries
#define TILE_ENCB 18
#define TILE_PW1  342
#define TILE_PW2  1206
#define TILE_PW3  1590

#define OBSP_STRIDE 24    // shorts/row (18 used: obs cols 0..17)
#define OBSH_STRIDE 32    // shorts/row (obs cols 16..47)
#define HS_STRIDE   104   // shorts/row (96 used: ext0|ext1|opp)
#define ENC_STRIDE  136   // shorts/row (4*32 used + 8 pad)
#define H_STRIDE    264   // shorts/row (256 used)

// smem arena (shorts): buf0 | buf1 (obs_hi overlaid) | obs_prop | Hs
#define SM_BUF1 8704
#define SM_OBSP 17408
#define SM_HS   18944
#define SM_TOT  25600     // 51,200 B -> alloc 53,248 (13 x 4 KiB) -> 3 blk/CU

typedef short bf16x8 __attribute__((ext_vector_type(8)));
typedef float f32x4  __attribute__((ext_vector_type(4)));
typedef float f32x2  __attribute__((ext_vector_type(2)));

__device__ __forceinline__ float lrelu(float x) { return fmaxf(x, NEG_SLOPE * x); }

__device__ __forceinline__ f32x4 lrelu4(f32x4 x) {
  return __builtin_elementwise_max(x, x * NEG_SLOPE);
}
__device__ __forceinline__ f32x4 splat4(float b) { return (f32x4){b, b, b, b}; }

__device__ __forceinline__ float u2f(unsigned int u) {
  union { unsigned int u; float f; } c; c.u = u; return c.f;
}

__device__ __forceinline__ float fast_tanh(float x) {
  x = fminf(10.f, fmaxf(-10.f, x));
  float e = __expf(2.f * x);
  return (e - 1.f) * __frcp_rn(e + 1.f);
}

// pack two f32 -> two bf16 (round-half-up) in one v_perm_b32
__device__ __forceinline__ unsigned int pk2bf(float a, float b) {
  union { float f; unsigned int u; } ca, cb; ca.f = a; cb.f = b;
  return __builtin_amdgcn_perm(cb.u + 0x8000u, ca.u + 0x8000u, 0x07060302u);
}

__device__ __forceinline__ unsigned short f2bf(float x) {  // RNE, prep only
  union { float f; unsigned int u; } c; c.f = x;
  unsigned int u = (c.u + 0x7fffu + ((c.u >> 16) & 1u)) >> 16;
  return (unsigned short)u;
}

// ---------------------------------------------------------------------------
// prep (v6): one thread = one frag row (lane) = 8 shorts = one uint4 store.
// B-frag layout: lane l holds B[k_pos=(l>>4)*8+j][n=l&15], j=0..7.
// kperm = (k_pos&1)*16 + (k_pos>>1) absorbs the pair-pack column permutation.
// ---------------------------------------------------------------------------
__global__ __launch_bounds__(256) void prep_kernel(
    const float* __restrict__ propW2, const float* __restrict__ extW1,
    const float* __restrict__ extW2,  const float* __restrict__ oppW1,
    const float* __restrict__ oppW2,  const float* __restrict__ piW1,
    const float* __restrict__ piW2,   const float* __restrict__ piW3,
    unsigned short* __restrict__ ws16)
{
  const int u = blockIdx.x * 256 + threadIdx.x;   // frag-row index
  if (u >= (WS_TOTAL >> 3)) return;
  const int lane = u & 63;
  const int t = u >> 6;                            // 512-short tile index
  const int lm = lane & 15;
  const int kbase = (lane >> 4) << 3;              // k_pos = kbase + j

  unsigned short o8[8];

  if (t < TILE_ENCB) {
    int s = t;
    const int nt2 = s & 1; s >>= 1;
    const int go = s % 3; const int p = s / 3;
    const int n = go * 32 + nt2 * 16 + lm;
    #pragma unroll
    for (int j = 0; j < 8; ++j) {
      const int d = 16 + kbase + j;
      float v;
      if (n < 64) {
        const int g = n >> 5, o = n & 31, i = d - 18 - 6 * g;
        v = (i >= 0 && i < 6) ? extW1[((p * 2 + g) * 6 + i) * 32 + o] : 0.f;
      } else {
        const int o = n - 64, i = d - 30;
        v = (i >= 0) ? oppW1[(p * 18 + i) * 32 + o] : 0.f;
      }
      o8[j] = f2bf(v);
    }
  } else if (t < TILE_PW1) {
    int s = t - TILE_ENCB;
    const int nt2 = s & 1; s >>= 1;
    const int br = s % 3; s /= 3;
    const int kt = s % 18; const int p = s / 18;
    const int n = kt * 32 + nt2 * 16 + lm;
    #pragma unroll
    for (int j = 0; j < 8; ++j) {
      const int k_pos = kbase + j;
      const int kperm = (k_pos & 1) * 16 + (k_pos >> 1);
      float v;
      if (br == 0)      { const int g = kt >> 1;   v = propW2[((p*9+g)*32 + k_pos)*64 + (n - g*64)]; }
      else if (br == 1) { const int g = (kt >= 9); v = extW2 [((p*2+g)*32 + kperm)*288 + (n - g*288)]; }
      else              {                          v = oppW2 [(p*32 + kperm)*576 + n]; }
      o8[j] = f2bf(v);
    }
  } else if (t < TILE_PW2) {
    int s = t - TILE_PW1;
    const int nt = s & 15; s >>= 4;
    const int kt = s % 18; const int p = s / 18;
    const int col = nt * 16 + lm;
    #pragma unroll
    for (int j = 0; j < 8; ++j) {
      const int k_pos = kbase + j;
      const int kperm = (k_pos & 1) * 16 + (k_pos >> 1);
      o8[j] = f2bf(piW1[(p * 576 + kt * 32 + kperm) * 256 + col]);
    }
  } else if (t < TILE_PW3) {
    int s = t - TILE_PW2;
    const int nt = s & 15; s >>= 4;
    const int kt = s & 7; const int p = s >> 3;
    const int col = nt * 16 + lm;
    #pragma unroll
    for (int j = 0; j < 8; ++j) {
      const int k_pos = kbase + j;
      const int kperm = (k_pos & 1) * 16 + (k_pos >> 1);
      o8[j] = f2bf(piW2[(p * 256 + kt * 32 + kperm) * 256 + col]);
    }
  } else {
    int s = t - TILE_PW3;
    const int kt = s & 7; const int p = s >> 3;
    #pragma unroll
    for (int j = 0; j < 8; ++j) {
      const int k_pos = kbase + j;
      const int kperm = (k_pos & 1) * 16 + (k_pos >> 1);
      o8[j] = (lm < 3) ? f2bf(piW3[(p * 256 + kt * 32 + kperm) * 3 + lm]) : (unsigned short)0;
    }
  }

  *(uint4*)&ws16[(size_t)u * 8] = *(const uint4*)o8;
}

// ---------------------------------------------------------------------------
__global__ __launch_bounds__(256, 3) void fused_kernel(
    const float* __restrict__ obs,
    const float* __restrict__ propW1, const float* __restrict__ propB1,
    const float* __restrict__ propB2,
    const float* __restrict__ extB1,  const float* __restrict__ extB2,
    const float* __restrict__ oppB1,  const float* __restrict__ oppB2,
    const unsigned short* __restrict__ wsAll,
    const float* __restrict__ b1v, const float* __restrict__ b2v,
    const float* __restrict__ b3v,
    float* __restrict__ out)
{
  __shared__ __align__(16) unsigned short smem[SM_TOT];  // 51,200 B arena
  unsigned short* obs_p = smem + SM_OBSP;  // [64][24] cols 0..17 (enc-long)
  unsigned short* obs_h = smem + SM_BUF1;  // [64][32] cols 16..47 (1a only, in buf1)
  unsigned short* Hsb   = smem + SM_HS;    // [64][104] (dead after enc)
  unsigned short* hbuf  = smem;            // [64][264] h1/h2 (overlays buf0+buf1)

  const unsigned short* b1aW = wsAll + OFF_B1A;
  const unsigned short* encB = wsAll + OFF_ENCB;
  const unsigned short* w1sw = wsAll + OFF_PW1;
  const unsigned short* w2sw = wsAll + OFF_PW2;
  const unsigned short* w3sw = wsAll + OFF_PW3;

  const int tid = threadIdx.x;
  const int p = blockIdx.y, brow = blockIdx.x;
  const int sbase = brow * 64;
  const int wv = tid >> 6, l = tid & 63, lm = l & 15, q = l >> 4;
  const f32x4 zz = {0.f, 0.f, 0.f, 0.f};

  // ---- phase 0: obs -> LDS bf16 (split prop/hi) ----
  {
    const int s = tid >> 2, c4 = tid & 3;
    if (c4 < 3) {
      const int c0 = c4 * 16;
      const float4* src = (const float4*)&obs[(sbase + s) * 144 + p * 48 + c0];
      float4 v0 = src[0], v1 = src[1], v2 = src[2], v3 = src[3];
      unsigned int pk[8];
      pk[0] = pk2bf(v0.x, v0.y); pk[1] = pk2bf(v0.z, v0.w);
      pk[2] = pk2bf(v1.x, v1.y); pk[3] = pk2bf(v1.z, v1.w);
      pk[4] = pk2bf(v2.x, v2.y); pk[5] = pk2bf(v2.z, v2.w);
      pk[6] = pk2bf(v3.x, v3.y); pk[7] = pk2bf(v3.z, v3.w);
      if (c4 == 0) {                       // cols 0..15 -> obs_prop
        *(uint4*)&obs_p[s * OBSP_STRIDE]     = *(uint4*)&pk[0];
        *(uint4*)&obs_p[s * OBSP_STRIDE + 8] = *(uint4*)&pk[4];
      } else if (c4 == 1) {                // cols 16..31 -> obs_hi; 16,17 -> obs_prop
        *(uint4*)&obs_h[s * OBSH_STRIDE]      = *(uint4*)&pk[0];
        *(uint4*)&obs_h[s * OBSH_STRIDE + 8]  = *(uint4*)&pk[4];
        *(unsigned int*)&obs_p[s * OBSP_STRIDE + 16] = pk[0];
      } else {                             // cols 32..47 -> obs_hi
        *(uint4*)&obs_h[s * OBSH_STRIDE + 16] = *(uint4*)&pk[0];
        *(uint4*)&obs_h[s * OBSH_STRIDE + 24] = *(uint4*)&pk[4];
      }
    }
  }
  __syncthreads();

  // ---- phase 1a: ext+opp layer-1 via MFMA (waves 1..3), bias in C ----
  if (wv >= 1) {
    const int go = wv - 1;                      // 0: ext0, 1: ext1, 2: opp
    bf16x8 af[4];
    #pragma unroll
    for (int ms = 0; ms < 4; ++ms)
      af[ms] = *(const bf16x8*)&obs_h[(ms * 16 + lm) * OBSH_STRIDE + q * 8];
    bf16x8 bf0 = *(const bf16x8*)&b1aW[((p * 3 + go) * 2 + 0) * 512 + l * 8];
    bf16x8 bf1 = *(const bf16x8*)&b1aW[((p * 3 + go) * 2 + 1) * 512 + l * 8];
    float bias0, bias1;
    if (go < 2) { bias0 = extB1[(p*2+go)*32 + lm]; bias1 = extB1[(p*2+go)*32 + 16 + lm]; }
    else        { bias0 = oppB1[p*32 + lm];        bias1 = oppB1[p*32 + 16 + lm]; }
    const f32x4 cb0 = splat4(bias0), cb1 = splat4(bias1);
    #pragma unroll
    for (int ms = 0; ms < 4; ++ms) {
      f32x4 c0 = lrelu4(__builtin_amdgcn_mfma_f32_16x16x32_bf16(af[ms], bf0, cb0, 0, 0, 0));
      f32x4 c1 = lrelu4(__builtin_amdgcn_mfma_f32_16x16x32_bf16(af[ms], bf1, cb1, 0, 0, 0));
      #pragma unroll
      for (int r = 0; r < 4; ++r)
        *(unsigned int*)&Hsb[(ms * 16 + q * 4 + r) * HS_STRIDE + go * 32 + lm * 2] =
            pk2bf(c0[r], c1[r]);
    }
  }

  // ---- pi L1 bias preload + acc init (bias in C) ----
  float b1r[4];
  #pragma unroll
  for (int nt = 0; nt < 4; ++nt) b1r[nt] = b1v[p * 256 + wv * 64 + nt * 16 + lm];
  f32x4 acc[4][4];
  #pragma unroll
  for (int a = 0; a < 4; ++a)
    #pragma unroll
    for (int b = 0; b < 4; ++b) acc[a][b] = splat4(b1r[b]);

  // enc producer: wave wv builds kt = g*4+wv into buf[g&1] (if active)
  auto produce = [&](int g) {
    const int nk = (g < 4) ? 4 : 2;
    if (wv >= nk) return;
    unsigned short* buf = smem + (g & 1) * SM_BUF1;
    const int kt = g * 4 + wv, ktloc = wv;
    const int gp = kt >> 1, ge = (kt >= 9) ? 1 : 0;

    // 1) prop-H A-frags first (prop weights die before W2 frags)
    bf16x8 apf[4];
    {
      f32x2 w0v[4], w1v[4], bbv[4];
      const float4* p4 = (const float4*)&propW1[(p * 9 + gp) * 64];
      float4 t0a = p4[q * 2],     t0b = p4[q * 2 + 1];
      float4 t1a = p4[8 + q * 2], t1b = p4[8 + q * 2 + 1];
      const float4* pb4 = (const float4*)&propB1[(p * 9 + gp) * 32];
      float4 tba = pb4[q * 2],    tbb = pb4[q * 2 + 1];
      w0v[0] = (f32x2){t0a.x, t0a.y}; w0v[1] = (f32x2){t0a.z, t0a.w};
      w0v[2] = (f32x2){t0b.x, t0b.y}; w0v[3] = (f32x2){t0b.z, t0b.w};
      w1v[0] = (f32x2){t1a.x, t1a.y}; w1v[1] = (f32x2){t1a.z, t1a.w};
      w1v[2] = (f32x2){t1b.x, t1b.y}; w1v[3] = (f32x2){t1b.z, t1b.w};
      bbv[0] = (f32x2){tba.x, tba.y}; bbv[1] = (f32x2){tba.z, tba.w};
      bbv[2] = (f32x2){tbb.x, tbb.y}; bbv[3] = (f32x2){tbb.z, tbb.w};
      #pragma unroll
      for (int ms = 0; ms < 4; ++ms) {
        const int row = ms * 16 + lm;
        const unsigned int xu = *(const unsigned int*)&obs_p[row * OBSP_STRIDE + 2 * gp];
        const f32x2 x0v = {u2f(xu << 16), u2f(xu << 16)};
        const f32x2 x1v = {u2f(xu & 0xffff0000u), u2f(xu & 0xffff0000u)};
        unsigned int au[4];
        #pragma unroll
        for (int jj = 0; jj < 4; ++jj) {
          f32x2 h = bbv[jj] + x0v * w0v[jj] + x1v * w1v[jj];
          h = __builtin_elementwise_max(h, h * NEG_SLOPE);
          au[jj] = pk2bf(h.x, h.y);
        }
        __builtin_memcpy(&apf[ms], au, 16);
      }
    }

    // 2) W2 B-frags + scalar branch biases
    const int ebase = (p * 18 + kt) * 6;
    bf16x8 wpf[2], wef[2], wof[2];
    float bp[2], be[2], bo[2];
    #pragma unroll
    for (int nt2 = 0; nt2 < 2; ++nt2) {
      wpf[nt2] = *(const bf16x8*)&encB[(ebase + nt2) * 512 + l * 8];
      wef[nt2] = *(const bf16x8*)&encB[(ebase + 2 + nt2) * 512 + l * 8];
      wof[nt2] = *(const bf16x8*)&encB[(ebase + 4 + nt2) * 512 + l * 8];
      const int nc = nt2 * 16 + lm;
      bp[nt2] = propB2[(p * 9 + gp) * 64 + (kt & 1) * 32 + nc];
      be[nt2] = extB2[(p * 2 + ge) * 288 + (kt - ge * 9) * 32 + nc];
      bo[nt2] = oppB2[p * 576 + kt * 32 + nc];
    }

    // 3) MFMAs sequenced per nt2, packed epilogue
    #pragma unroll
    for (int ms = 0; ms < 4; ++ms) {
      const int row = ms * 16 + lm;
      bf16x8 ae = *(const bf16x8*)&Hsb[row * HS_STRIDE + ge * 32 + q * 8];
      bf16x8 ao = *(const bf16x8*)&Hsb[row * HS_STRIDE + 64 + q * 8];
      f32x4 s0, s1;
      {
        f32x4 cp = __builtin_amdgcn_mfma_f32_16x16x32_bf16(apf[ms], wpf[0], zz, 0, 0, 0);
        f32x4 ce = __builtin_amdgcn_mfma_f32_16x16x32_bf16(ae,      wef[0], zz, 0, 0, 0);
        f32x4 co = __builtin_amdgcn_mfma_f32_16x16x32_bf16(ao,      wof[0], zz, 0, 0, 0);
        s0 = lrelu4(cp + splat4(bp[0])) + lrelu4(ce + splat4(be[0])) + lrelu4(co + splat4(bo[0]));
      }
      {
        f32x4 cp = __builtin_amdgcn_mfma_f32_16x16x32_bf16(apf[ms], wpf[1], zz, 0, 0, 0);
        f32x4 ce = __builtin_amdgcn_mfma_f32_16x16x32_bf16(ae,      wef[1], zz, 0, 0, 0);
        f32x4 co = __builtin_amdgcn_mfma_f32_16x16x32_bf16(ao,      wof[1], zz, 0, 0, 0);
        s1 = lrelu4(cp + splat4(bp[1])) + lrelu4(ce + splat4(be[1])) + lrelu4(co + splat4(bo[1]));
      }
      #pragma unroll
      for (int r = 0; r < 4; ++r)
        *(unsigned int*)&buf[(ms * 16 + q * 4 + r) * ENC_STRIDE + ktloc * 32 + lm * 2] =
            pk2bf(s0[r], s1[r]);
    }
  };

  // ---- software pipeline: produce(0); then {produce(g+1); consume(g)} ----
  __syncthreads();            // obs/Hs (phase 0/1a) visible
  produce(0);                 // writes buf0 (obs_h in buf1 still intact)
  __syncthreads();            // buf0 ready

  for (int g = 0; g < 5; ++g) {
    if (g < 4) produce(g + 1);               // writes buf[(g+1)&1]

    // consume(g): pi L1 partial from buf[g&1]  (overlaps produce via scheduler)
    const unsigned short* buf = smem + (g & 1) * SM_BUF1;
    const int nk = (g < 4) ? 4 : 2;
    for (int ktloc = 0; ktloc < nk; ++ktloc) {
      const int kt = g * 4 + ktloc;
      bf16x8 afr[4], bfr[4];
      #pragma unroll
      for (int ms = 0; ms < 4; ++ms)
        afr[ms] = *(const bf16x8*)&buf[(ms * 16 + lm) * ENC_STRIDE + ktloc * 32 + q * 8];
      const int wb = ((p * 18 + kt) * 16 + wv * 4) * 512 + l * 8;
      #pragma unroll
      for (int nt = 0; nt < 4; ++nt)
        bfr[nt] = *(const bf16x8*)&w1sw[wb + nt * 512];
      #pragma unroll
      for (int ms = 0; ms < 4; ++ms)
        #pragma unroll
        for (int nt = 0; nt < 4; ++nt)
          acc[ms][nt] = __builtin_amdgcn_mfma_f32_16x16x32_bf16(afr[ms], bfr[nt], acc[ms][nt], 0, 0, 0);
    }
    __syncthreads();   // produce(g+1) done for all waves; consume(g) reads done
  }

  // ---- h1 epilogue (packed lrelu; overwrites enc bufs: dead) ----
  #pragma unroll
  for (int ms = 0; ms < 4; ++ms)
    #pragma unroll
    for (int pi2 = 0; pi2 < 2; ++pi2) {
      f32x4 a0 = lrelu4(acc[ms][pi2 * 2]);
      f32x4 a1 = lrelu4(acc[ms][pi2 * 2 + 1]);
      #pragma unroll
      for (int r = 0; r < 4; ++r)
        *(unsigned int*)&hbuf[(ms * 16 + q * 4 + r) * H_STRIDE + (wv * 2 + pi2) * 32 + lm * 2] =
            pk2bf(a0[r], a1[r]);
    }
  __syncthreads();

  // ---- pi L2: 256 -> 256 (bias in C) ----
  {
    float b2r[4];
    #pragma unroll
    for (int nt = 0; nt < 4; ++nt) b2r[nt] = b2v[p * 256 + wv * 64 + nt * 16 + lm];
    #pragma unroll
    for (int a = 0; a < 4; ++a)
      #pragma unroll
      for (int b = 0; b < 4; ++b) acc[a][b] = splat4(b2r[b]);
  }
  for (int kt = 0; kt < 8; ++kt) {
    bf16x8 afr[4], bfr[4];
    #pragma unroll
    for (int ms = 0; ms < 4; ++ms)
      afr[ms] = *(const bf16x8*)&hbuf[(ms * 16 + lm) * H_STRIDE + kt * 32 + q * 8];
    const int wb = ((p * 8 + kt) * 16 + wv * 4) * 512 + l * 8;
    #pragma unroll
    for (int nt = 0; nt < 4; ++nt)
      bfr[nt] = *(const bf16x8*)&w2sw[wb + nt * 512];
    #pragma unroll
    for (int ms = 0; ms < 4; ++ms)
      #pragma unroll
      for (int nt = 0; nt < 4; ++nt)
        acc[ms][nt] = __builtin_amdgcn_mfma_f32_16x16x32_bf16(afr[ms], bfr[nt], acc[ms][nt], 0, 0, 0);
  }
  __syncthreads();                 // all h1 reads complete before overwrite
  #pragma unroll
  for (int ms = 0; ms < 4; ++ms)
    #pragma unroll
    for (int pi2 = 0; pi2 < 2; ++pi2) {
      f32x4 a0 = lrelu4(acc[ms][pi2 * 2]);
      f32x4 a1 = lrelu4(acc[ms][pi2 * 2 + 1]);
      #pragma unroll
      for (int r = 0; r < 4; ++r)
        *(unsigned int*)&hbuf[(ms * 16 + q * 4 + r) * H_STRIDE + (wv * 2 + pi2) * 32 + lm * 2] =
            pk2bf(a0[r], a1[r]);
    }
  __syncthreads();

  // ---- pi L3: 256 -> 3 (N padded to 16) + tanh, bias in C ----
  const float bias3 = (lm < 3) ? b3v[p * 3 + lm] : 0.f;
  f32x4 a3 = splat4(bias3);
  for (int kt = 0; kt < 8; ++kt) {
    bf16x8 afr = *(const bf16x8*)&hbuf[(wv * 16 + lm) * H_STRIDE + kt * 32 + q * 8];
    bf16x8 bfr = *(const bf16x8*)&w3sw[((p * 8 + kt) * 64 + l) * 8];
    a3 = __builtin_amdgcn_mfma_f32_16x16x32_bf16(afr, bfr, a3, 0, 0, 0);
  }
  if (lm < 3) {
    #pragma unroll
    for (int r = 0; r < 4; ++r) {
      const int s = wv * 16 + q * 4 + r;
      out[(sbase + s) * 9 + p * 3 + lm] = fast_tanh(a3[r]);
    }
  }
}

// ---------------------------------------------------------------------------
extern "C" void kernel_launch(void* const* d_in, const int* in_sizes, int n_in,
                              void* d_out, int out_size, void* d_ws, size_t ws_size,
                              hipStream_t stream)
{
  (void)in_sizes; (void)n_in; (void)out_size; (void)ws_size;
  const float* obs    = (const float*)d_in[0];
  const float* propW1 = (const float*)d_in[1];
  const float* propB1 = (const float*)d_in[2];
  const float* propW2 = (const float*)d_in[3];
  const float* propB2 = (const float*)d_in[4];
  const float* extW1  = (const float*)d_in[5];
  const float* extB1  = (const float*)d_in[6];
  const float* extW2  = (const float*)d_in[7];
  const float* extB2  = (const float*)d_in[8];
  const float* oppW1  = (const float*)d_in[9];
  const float* oppB1  = (const float*)d_in[10];
  const float* oppW2  = (const float*)d_in[11];
  const float* oppB2  = (const float*)d_in[12];
  const float* piW1   = (const float*)d_in[13];
  const float* piB1   = (const float*)d_in[14];
  const float* piW2   = (const float*)d_in[15];
  const float* piB2   = (const float*)d_in[16];
  const float* piW3   = (const float*)d_in[17];
  const float* piB3   = (const float*)d_in[18];
  float* out = (float*)d_out;
  unsigned short* ws16 = (unsigned short*)d_ws;

  prep_kernel<<<dim3(((WS_TOTAL >> 3) + 255) / 256), dim3(256), 0, stream>>>(
      propW2, extW1, extW2, oppW1, oppW2, piW1, piW2, piW3, ws16);

  fused_kernel<<<dim3(65536 / 64, 3), dim3(256), 0, stream>>>(
      obs, propW1, propB1, propB2, extB1, extB2, oppB1, oppB2,
      ws16, piB1, piB2, piB3, out);
}